// Round 14
// baseline (174.133 us; speedup 1.0000x reference)
//
#include <hip/hip_runtime.h>
#include <math.h>

// Problem constants
#define B_  4
#define C_  256
#define N_  4096
#define CK_ 32
#define CV_ 128

typedef __attribute__((ext_vector_type(8))) short short8;  // 8 bf16 = 4 VGPRs
typedef __attribute__((ext_vector_type(4))) float f32x4;   // MFMA C/D frag
typedef unsigned short u16;
typedef unsigned int   u32;

static constexpr float LOG2E = 1.4426950408889634f;

static __device__ __forceinline__ u16 f2bf(float f) {       // fp32 -> bf16 RNE
    u32 u = __float_as_uint(f);
    u = (u + 0x7FFFu + ((u >> 16) & 1u)) >> 16;
    return (u16)u;
}
static __device__ __forceinline__ float bf2f(u16 h) {
    return __uint_as_float(((u32)h) << 16);
}

// native transcendentals
static __device__ __forceinline__ float fexp2(float x) {
#if __has_builtin(__builtin_amdgcn_exp2f)
    return __builtin_amdgcn_exp2f(x);
#else
    float r; asm("v_exp_f32 %0, %1\n\ts_nop 0" : "=v"(r) : "v"(x)); return r;
#endif
}
static __device__ __forceinline__ float frcp(float x) {
#if __has_builtin(__builtin_amdgcn_rcpf)
    return __builtin_amdgcn_rcpf(x);
#else
    float r; asm("v_rcp_f32 %0, %1\n\ts_nop 0" : "=v"(r) : "v"(x)); return r;
#endif
}
// pack two fp32 -> 2x bf16 (RNE), lo = a, hi = b
static __device__ __forceinline__ u32 cvt_pk_bf16(float a, float b) {
    u32 r; asm("v_cvt_pk_bf16_f32 %0, %1, %2" : "=v"(r) : "v"(a), "v"(b));
    return r;
}

// ---------------------------------------------------------------------------
// Kernel 0: prep = x transpose/convert  +  weight convert (merged).
// ---------------------------------------------------------------------------
__global__ __launch_bounds__(256) void prep_kernel(
    const float* __restrict__ x, u16* __restrict__ xT16,
    const float* __restrict__ theta_w, const float* __restrict__ phi_w,
    const float* __restrict__ g_w,     const float* __restrict__ o_w,
    u16* __restrict__ W16, u16* __restrict__ ow16)
{
    if (blockIdx.x >= N_ / 64) {
        const int base = (((blockIdx.x - N_ / 64) * 16 + blockIdx.y * 4 + blockIdx.z) * 256
                          + threadIdx.x) * 4;
        #pragma unroll
        for (int e0 = 0; e0 < 4; ++e0) {
            const int e = base + e0;
            if (e < 8192)        W16[e] = f2bf(theta_w[e] * LOG2E);
            else if (e < 16384)  W16[e] = f2bf(phi_w[e - 8192]);
            else if (e < 49152)  W16[e] = f2bf(g_w[e - 16384]);
            else                 ow16[e - 49152] = f2bf(o_w[e - 49152]);
        }
        return;
    }

    const int b = blockIdx.z, c0 = blockIdx.y * 64, n0 = blockIdx.x * 64;
    const int t = threadIdx.x;
    __shared__ float tile[64][65];

    const int cr = t >> 4, nc = (t & 15) * 4;
    #pragma unroll
    for (int it = 0; it < 4; ++it) {
        const float4 v = *(const float4*)(x + (size_t)(b * C_ + c0 + cr + it * 16) * N_ + n0 + nc);
        tile[cr + it * 16][nc + 0] = v.x; tile[cr + it * 16][nc + 1] = v.y;
        tile[cr + it * 16][nc + 2] = v.z; tile[cr + it * 16][nc + 3] = v.w;
    }
    __syncthreads();
    const int n = t >> 2, cg = (t & 3) * 16;
    union { u16 us[16]; uint4 u4[2]; } pk;
    #pragma unroll
    for (int e = 0; e < 16; ++e) pk.us[e] = f2bf(tile[cg + e][n]);
    uint4* dst = (uint4*)(xT16 + (size_t)(b * N_ + n0 + n) * C_ + c0 + cg);
    dst[0] = pk.u4[0]; dst[1] = pk.u4[1];
}

// ---------------------------------------------------------------------------
// Kernel 1: projections via MFMA. theta_t/phi_t [n][32] row-major. g stored
// UNSCALED in the PV B-fragment-tiled layout:
//   g2[((b*8 + ctile)*128 + jchunk)*512 + lane*8 + slot]
// ---------------------------------------------------------------------------
__global__ __launch_bounds__(256) void proj_mfma_kernel(
    const u16* __restrict__ xT16, const u16* __restrict__ W16,
    const float* __restrict__ theta_b, const float* __restrict__ phi_b,
    const float* __restrict__ g_b,
    u16* __restrict__ theta_t, u16* __restrict__ phi_t, u16* __restrict__ g2)
{
    const int b = blockIdx.y, n0 = blockIdx.x * 64;
    const int w = threadIdx.x >> 6, lane = threadIdx.x & 63;
    const int lr = lane & 15, q = lane >> 4;
    const f32x4 zf = {0.f, 0.f, 0.f, 0.f};

    // ---- theta/phi: wave w owns pixel m-tile w ----
    const u16* xrow = xT16 + (size_t)(b * N_ + n0 + w * 16 + lr) * C_;
    f32x4 acc[4];
    #pragma unroll
    for (int nt = 0; nt < 4; ++nt) acc[nt] = zf;
    for (int ks = 0; ks < 8; ++ks) {
        const short8 aX = *(const short8*)(xrow + ks * 32 + q * 8);
        #pragma unroll
        for (int nt = 0; nt < 4; ++nt) {
            const short8 bW = *(const short8*)(W16 + (size_t)(nt * 16 + lr) * C_ + ks * 32 + q * 8);
            acc[nt] = __builtin_amdgcn_mfma_f32_16x16x32_bf16(aX, bW, acc[nt], 0, 0, 0);
        }
    }
    #pragma unroll
    for (int nt = 0; nt < 4; ++nt) {
        const int o = nt * 16 + lr;
        #pragma unroll
        for (int reg = 0; reg < 4; ++reg) {
            const int n = n0 + w * 16 + q * 4 + reg;
            if (nt < 2)
                theta_t[(size_t)(b * N_ + n) * CK_ + o] = f2bf(acc[nt][reg] + theta_b[o] * LOG2E);
            else
                phi_t[(size_t)(b * N_ + n) * CK_ + (o - 32)] = f2bf(acc[nt][reg] + phi_b[o - 32]);
        }
    }

    // ---- g: wave w owns c m-tiles {2w, 2w+1}; store in frag-tiled layout ----
    #pragma unroll
    for (int mp = 0; mp < 2; ++mp) {
        const int ctile = w * 2 + mp;
        const int crow = ctile * 16;
        f32x4 ag[4];
        #pragma unroll
        for (int nt = 0; nt < 4; ++nt) ag[nt] = zf;
        for (int ks = 0; ks < 8; ++ks) {
            const short8 aW = *(const short8*)(W16 + (size_t)(64 + crow + lr) * C_ + ks * 32 + q * 8);
            #pragma unroll
            for (int nt = 0; nt < 4; ++nt) {
                const short8 bX = *(const short8*)(xT16 + (size_t)(b * N_ + n0 + nt * 16 + lr) * C_ + ks * 32 + q * 8);
                ag[nt] = __builtin_amdgcn_mfma_f32_16x16x32_bf16(aW, bX, ag[nt], 0, 0, 0);
            }
        }
        #pragma unroll
        for (int nt = 0; nt < 4; ++nt) {
            const int jchunk = (n0 >> 5) + (nt >> 1);
            const int lhi = (nt & 1) * 2 + (lr >> 3);
            #pragma unroll
            for (int reg = 0; reg < 4; ++reg) {
                const int c = crow + q * 4 + reg;
                const int lane2 = (q * 4 + reg) + 16 * lhi;
                g2[((size_t)(b * 8 + ctile) * 128 + jchunk) * 512 + lane2 * 8 + (lr & 7)]
                    = f2bf(ag[nt][reg] + g_b[c]);
            }
        }
    }
}

// ---------------------------------------------------------------------------
// Kernel 2: Z[b][j] = sum_i exp2(S[i][j]) via MFMA. 8 phi-frags per wave
// (128 j) -> each theta A-load feeds 8 MFMAs. Grid (N/128, 4, B).
// ---------------------------------------------------------------------------
__global__ __launch_bounds__(256) void colstats_kernel(
    const u16* __restrict__ theta_t, const u16* __restrict__ phi_t,
    float* __restrict__ Z)
{
    const int b  = blockIdx.z;
    const int j0 = blockIdx.x * 128;
    const int istart = blockIdx.y * (N_ / 4);
    const int tid = threadIdx.x;
    const int w = tid >> 6, lane = tid & 63;
    const int lr = lane & 15, q = lane >> 4;

    short8 bF[8];
    #pragma unroll
    for (int jt = 0; jt < 8; ++jt)
        bF[jt] = *(const short8*)(phi_t + (size_t)(b * N_ + j0 + jt * 16 + lr) * CK_ + q * 8);

    const u16* thp = theta_t + (size_t)b * N_ * CK_;
    const f32x4 zero = {0.f, 0.f, 0.f, 0.f};
    float za[8];
    #pragma unroll
    for (int jt = 0; jt < 8; ++jt) za[jt] = 0.f;

    for (int i = istart + w * 16; i < istart + N_ / 4; i += 64) {
        const short8 aF = *(const short8*)(thp + (size_t)(i + lr) * CK_ + q * 8);
        #pragma unroll
        for (int jt = 0; jt < 8; ++jt) {
            const f32x4 S = __builtin_amdgcn_mfma_f32_16x16x32_bf16(aF, bF[jt], zero, 0, 0, 0);
            za[jt] += fexp2(S[0]) + fexp2(S[1]) + fexp2(S[2]) + fexp2(S[3]);
        }
    }
    #pragma unroll
    for (int jt = 0; jt < 8; ++jt) {
        za[jt] += __shfl_xor(za[jt], 16);
        za[jt] += __shfl_xor(za[jt], 32);
    }
    if (lane < 16) {
        #pragma unroll
        for (int jt = 0; jt < 8; ++jt)
            atomicAdd(&Z[(size_t)b * N_ + j0 + jt * 16 + lr], za[jt]);
    }
}

// ---------------------------------------------------------------------------
// Kernel 3: fold 1/Z into g2 (in place, bf16). R5-proven.
// ---------------------------------------------------------------------------
__global__ __launch_bounds__(256) void gscale_kernel(
    u16* __restrict__ g2, const float* __restrict__ Z)
{
    const size_t idx = ((size_t)blockIdx.x * 256 + threadIdx.x) * 8;
    const int b = (int)(idx >> 19);
    const int j = (int)(((idx >> 9) & 127) * 32 + ((idx >> 7) & 3) * 8);
    uint4 raw = *(const uint4*)(g2 + idx);
    const float4 z0 = *(const float4*)(Z + (size_t)b * N_ + j);
    const float4 z1 = *(const float4*)(Z + (size_t)b * N_ + j + 4);
    const float zz[8] = {z0.x, z0.y, z0.z, z0.w, z1.x, z1.y, z1.z, z1.w};
    u16* pr = (u16*)&raw;
    union { u16 us[8]; uint4 u4; } pk;
    #pragma unroll
    for (int k = 0; k < 8; ++k) pk.us[k] = f2bf(bf2f(pr[k]) * frcp(zz[k]));
    *(uint4*)(g2 + idx) = pk.u4;
}

// ---------------------------------------------------------------------------
// Kernel 4: o_pre partial (R12-proven: LDS E-sharing across c + w0 phi
// broadcast via Ph). Unchanged.
// ---------------------------------------------------------------------------
__global__ __launch_bounds__(256, 1) void opre_kernel(
    const u16* __restrict__ theta_t, const u16* __restrict__ phi_t,
    const u16* __restrict__ g2,
    float* __restrict__ o_p0, float* __restrict__ o_p1, u16* __restrict__ opb)
{
    const int bx = blockIdx.x;
    const int igg = bx & 31, jq = (bx >> 5) & 3, b = bx >> 7;
    const int w = threadIdx.x >> 6, lane = threadIdx.x & 63;
    const int lr = lane & 15, q = lane >> 4;
    const int i0 = igg * 128;
    const f32x4 zf = {0.f, 0.f, 0.f, 0.f};

    __shared__ u16 El[2][8 * 512];     // [buf][it*512 + lane*8], 2 x 8 KB
    __shared__ u16 Ph[2][1024];        // [slot][frag(2) x lane*8], 2 x 2 KB

    // theta B-frags for MY 2 S-i-tiles (it = 2w, 2w+1)
    const short8 bT0 = *(const short8*)(theta_t + (size_t)(b * N_ + i0 + (2 * w) * 16 + lr) * CK_ + q * 8);
    const short8 bT1 = *(const short8*)(theta_t + (size_t)(b * N_ + i0 + (2 * w + 1) * 16 + lr) * CK_ + q * 8);

    // phi A-frag row permutation (row r <-> j = (r>>2)*8 + (r&3))
    const int ja = (lr >> 2) * 8 + (lr & 3);
    const int jstart = jq * (N_ / 4);
    const u16* pA = phi_t + ((size_t)(b * N_) + jstart + ja) * CK_ + q * 8;
    const u16* pG = g2 + ((size_t)(b * 8 + w * 2) * 128 + jq * 32) * 512 + lane * 8;

    f32x4 acc[8][2];
    #pragma unroll
    for (int it = 0; it < 8; ++it) { acc[it][0] = zf; acc[it][1] = zf; }

    // phi prefetch: wave 0 only (shared via Ph). g prefetch: all waves.
    short8 A0a = {}, A1a = {}, A0b = {}, A1b = {};
    if (w == 0) {
        A0a = *(const short8*)(pA);
        A1a = *(const short8*)(pA + 4 * CK_);
        A0b = *(const short8*)(pA + 32 * CK_);
        A1b = *(const short8*)(pA + 36 * CK_);
        *(short8*)(&Ph[0][lane * 8])       = A0a;    // publish phi(0)
        *(short8*)(&Ph[0][512 + lane * 8]) = A1a;
    }
    short8 G0a = *(const short8*)(pG);
    short8 G1a = *(const short8*)(pG + 128 * 512);
    short8 G0b = *(const short8*)(pG + 512);
    short8 G1b = *(const short8*)(pG + 128 * 512 + 512);
    __syncthreads();

    u16* const myE0 = &El[0][(2 * w) * 512 + lane * 8];
    u16* const myE1 = &El[0][(2 * w + 1) * 512 + lane * 8];
    const int bufstep = 8 * 512;       // u16 offset between E buffers

// AW* = regs holding phi(K+1) (publish now); AL* = regs to refill with phi(K+2)
#define OPRE_CHUNK(K, BUF, AW0, AW1, AL0, AL1, G0r, G1r)                           \
    {                                                                               \
        const int kn = ((K) + 2) & 31;                                              \
        if (w == 0) {                                                               \
            *(short8*)(&Ph[(BUF) ^ 1][lane * 8])       = AW0;                       \
            *(short8*)(&Ph[(BUF) ^ 1][512 + lane * 8]) = AW1;                       \
            AL0 = *(const short8*)(pA + (size_t)kn * (32 * CK_));                   \
            AL1 = *(const short8*)(pA + (size_t)kn * (32 * CK_) + 4 * CK_);         \
        }                                                                           \
        const short8 cG0 = G0r, cG1 = G1r;                                          \
        G0r = *(const short8*)(pG + kn * 512);                                      \
        G1r = *(const short8*)(pG + 128 * 512 + kn * 512);                          \
        const short8 cA0 = *(const short8*)(&Ph[BUF][lane * 8]);                    \
        const short8 cA1 = *(const short8*)(&Ph[BUF][512 + lane * 8]);              \
        /* S + exp for my 2 i-tiles only */                                         \
        const f32x4 Sa0 = __builtin_amdgcn_mfma_f32_16x16x32_bf16(cA0, bT0, zf, 0, 0, 0); \
        const f32x4 Sb0 = __builtin_amdgcn_mfma_f32_16x16x32_bf16(cA1, bT0, zf, 0, 0, 0); \
        const f32x4 Sa1 = __builtin_amdgcn_mfma_f32_16x16x32_bf16(cA0, bT1, zf, 0, 0, 0); \
        const f32x4 Sb1 = __builtin_amdgcn_mfma_f32_16x16x32_bf16(cA1, bT1, zf, 0, 0, 0); \
        union { u32 u[4]; short8 s8; } e0, e1;                                      \
        e0.u[0] = cvt_pk_bf16(fexp2(Sa0[0]), fexp2(Sa0[1]));                        \
        e0.u[1] = cvt_pk_bf16(fexp2(Sa0[2]), fexp2(Sa0[3]));                        \
        e0.u[2] = cvt_pk_bf16(fexp2(Sb0[0]), fexp2(Sb0[1]));                        \
        e0.u[3] = cvt_pk_bf16(fexp2(Sb0[2]), fexp2(Sb0[3]));                        \
        e1.u[0] = cvt_pk_bf16(fexp2(Sa1[0]), fexp2(Sa1[1]));                        \
        e1.u[1] = cvt_pk_bf16(fexp2(Sa1[2]), fexp2(Sa1[3]));                        \
        e1.u[2] = cvt_pk_bf16(fexp2(Sb1[0]), fexp2(Sb1[1]));                        \
        e1.u[3] = cvt_pk_bf16(fexp2(Sb1[2]), fexp2(Sb1[3]));                        \
        *(short8*)(myE0 + (BUF) * bufstep) = e0.s8;                                 \
        *(short8*)(myE1 + (BUF) * bufstep) = e1.s8;                                 \
        __syncthreads();                                                            \
        _Pragma("unroll")                                                           \
        for (int it = 0; it < 8; ++it) {                                            \
            const short8 eF = *(const short8*)(&El[BUF][it * 512 + lane * 8]);      \
            acc[it][0] = __builtin_amdgcn_mfma_f32_16x16x32_bf16(eF, cG0, acc[it][0], 0, 0, 0); \
            acc[it][1] = __builtin_amdgcn_mfma_f32_16x16x32_bf16(eF, cG1, acc[it][1], 0, 0, 0); \
        }                                                                           \
    }

    for (int k = 0; k < 32; k += 2) {
        OPRE_CHUNK(k,     0, A0b, A1b, A0a, A1a, G0a, G1a)   // publish phi(k+1)=b, refill a
        OPRE_CHUNK(k + 1, 1, A0a, A1a, A0b, A1b, G0b, G1b)   // publish phi(k+2)=a, refill b
    }
#undef OPRE_CHUNK

    // store partials in final's B-frag-tiled layout (R9 formulas, ch := w):
    // [(((b*256 + ntile)*4 + ks)*64 + lane')*8 + slot], ks = w
    if (jq < 2) {
        float* op = (jq ? o_p1 : o_p0);
        #pragma unroll
        for (int it = 0; it < 8; ++it) {
            const size_t tb = ((size_t)(b * 256 + (i0 >> 4) + it) * 4 + w) * 512;
            #pragma unroll
            for (int ct = 0; ct < 2; ++ct) {
                #pragma unroll
                for (int reg = 0; reg < 4; ++reg) {
                    const int lane2 = (q * 4 + reg) + 16 * (ct * 2 + (lr >> 3));
                    op[tb + lane2 * 8 + (lr & 7)] = acc[it][ct][reg];
                }
            }
        }
    } else {
        u16* ob = opb + (size_t)(jq - 2) * ((size_t)B_ * N_ * CV_);
        #pragma unroll
        for (int it = 0; it < 8; ++it) {
            const size_t tb = ((size_t)(b * 256 + (i0 >> 4) + it) * 4 + w) * 512;
            #pragma unroll
            for (int ct = 0; ct < 2; ++ct) {
                #pragma unroll
                for (int reg = 0; reg < 4; ++reg) {
                    const int lane2 = (q * 4 + reg) + 16 * (ct * 2 + (lr >> 3));
                    ob[tb + lane2 * 8 + (lr & 7)] = f2bf(acc[it][ct][reg]);
                }
            }
        }
    }
}

// ---------------------------------------------------------------------------
// Kernel 5: out = x + gamma * (o_w @ (o_p0 + o_p1 + opb0 + opb1) + o_b).
// (R9-proven, unchanged.) Grid (N/32, B) = 512 blocks, 256 thr.
// ---------------------------------------------------------------------------
__global__ __launch_bounds__(256) void final_mfma_kernel(
    const float* __restrict__ o_p0, const float* __restrict__ o_p1,
    const u16* __restrict__ opb,
    const u16* __restrict__ ow16, const float* __restrict__ o_b,
    const float* __restrict__ gamma, const float* __restrict__ x,
    float* __restrict__ out)
{
    const int b = blockIdx.y, n0 = blockIdx.x * 32;
    const int w = threadIdx.x >> 6, lane = threadIdx.x & 63;
    const int lr = lane & 15, q = lane >> 4;
    const f32x4 zf = {0.f, 0.f, 0.f, 0.f};
    const size_t QS = (size_t)B_ * N_ * CV_;

    f32x4 acc[4][2];
    #pragma unroll
    for (int mt = 0; mt < 4; ++mt)
        #pragma unroll
        for (int nt = 0; nt < 2; ++nt) acc[mt][nt] = zf;

    for (int ks = 0; ks < 4; ++ks) {
        short8 bP[2];
        #pragma unroll
        for (int nt = 0; nt < 2; ++nt) {
            const size_t base = (((size_t)(b * 256 + (n0 >> 4) + nt) * 4 + ks) * 64 + lane) * 8;
            const float4 a0 = *(const float4*)(o_p0 + base);
            const float4 a1 = *(const float4*)(o_p0 + base + 4);
            const float4 c0 = *(const float4*)(o_p1 + base);
            const float4 c1 = *(const float4*)(o_p1 + base + 4);
            union { u16 us[8]; uint4 u4; } w2, w3;
            w2.u4 = *(const uint4*)(opb + base);
            w3.u4 = *(const uint4*)(opb + QS + base);
            float s[8] = {a0.x + c0.x, a0.y + c0.y, a0.z + c0.z, a0.w + c0.w,
                          a1.x + c1.x, a1.y + c1.y, a1.z + c1.z, a1.w + c1.w};
            #pragma unroll
            for (int e = 0; e < 8; ++e)
                s[e] += bf2f(w2.us[e]) + bf2f(w3.us[e]);
            union { u32 u[4]; short8 s8; } pk;
            pk.u[0] = cvt_pk_bf16(s[0], s[1]);
            pk.u[1] = cvt_pk_bf16(s[2], s[3]);
            pk.u[2] = cvt_pk_bf16(s[4], s[5]);
            pk.u[3] = cvt_pk_bf16(s[6], s[7]);
            bP[nt] = pk.s8;
        }
        #pragma unroll
        for (int mt = 0; mt < 4; ++mt) {
            const short8 aW = *(const short8*)(ow16 + (size_t)((w * 4 + mt) * 16 + lr) * CV_ + ks * 32 + q * 8);
            #pragma unroll
            for (int nt = 0; nt < 2; ++nt)
                acc[mt][nt] = __builtin_amdgcn_mfma_f32_16x16x32_bf16(aW, bP[nt], acc[mt][nt], 0, 0, 0);
        }
    }

    const float gm = gamma[0];
    #pragma unroll
    for (int mt = 0; mt < 4; ++mt) {
        #pragma unroll
        for (int nt = 0; nt < 2; ++nt) {
            #pragma unroll
            for (int reg = 0; reg < 4; ++reg) {
                const int oc = (w * 4 + mt) * 16 + q * 4 + reg;
                const int n = n0 + nt * 16 + lr;
                const size_t off = (size_t)(b * C_ + oc) * N_ + n;
                out[off] = x[off] + gm * (acc[mt][nt][reg] + o_b[oc]);
            }
        }
    }
}

// ---------------------------------------------------------------------------
extern "C" void kernel_launch(void* const* d_in, const int* in_sizes, int n_in,
                              void* d_out, int out_size, void* d_ws, size_t ws_size,
                              hipStream_t stream)
{
    const float* x       = (const float*)d_in[0];
    const float* theta_w = (const float*)d_in[1];
    const float* theta_b = (const float*)d_in[2];
    const float* phi_w   = (const float*)d_in[3];
    const float* phi_b   = (const float*)d_in[4];
    const float* g_w     = (const float*)d_in[5];
    const float* g_b     = (const float*)d_in[6];
    const float* o_w     = (const float*)d_in[7];
    const float* o_b     = (const float*)d_in[8];
    const float* gamma   = (const float*)d_in[9];
    float* out = (float*)d_out;

    // workspace: xT16 8MB (reused by opre as 2x bf16 partial quarters) |
    //            W16 96KB | ow16 64KB | theta_t 1MB | phi_t 1MB | g2 4MB |
    //            Z 64KB | o_p0 8MB | o_p1 8MB   (~30 MB total)
    u16* xT16    = (u16*)d_ws;
    u16* W16     = xT16 + (size_t)B_ * N_ * C_;
    u16* ow16    = W16 + 192 * C_;
    u16* theta_t = ow16 + C_ * CV_;
    u16* phi_t   = theta_t + (size_t)B_ * N_ * CK_;
    u16* g2      = phi_t + (size_t)B_ * N_ * CK_;
    float* Z     = (float*)(g2 + (size_t)B_ * CV_ * N_);
    float* o_p0  = Z + (size_t)B_ * N_;
    float* o_p1  = o_p0 + (size_t)B_ * N_ * CV_;
    u16* opb     = xT16;   // 2 x 4MB bf16 partial quarters, alias (xT dead after proj)

    hipMemsetAsync(Z, 0, (size_t)B_ * N_ * sizeof(float), stream);

    prep_kernel<<<dim3(N_ / 64 + 5, C_ / 64, B_), 256, 0, stream>>>(
        x, xT16, theta_w, phi_w, g_w, o_w, W16, ow16);
    proj_mfma_kernel<<<dim3(N_ / 64, B_), 256, 0, stream>>>(
        xT16, W16, theta_b, phi_b, g_b, theta_t, phi_t, g2);
    colstats_kernel<<<dim3(N_ / 128, 4, B_), 256, 0, stream>>>(theta_t, phi_t, Z);
    gscale_kernel<<<dim3((B_ * CV_ * N_) / 2048), 256, 0, stream>>>(g2, Z);
    opre_kernel<<<dim3(512), 256, 0, stream>>>(theta_t, phi_t, g2, o_p0, o_p1, opb);
    final_mfma_kernel<<<dim3(N_ / 32, B_), 256, 0, stream>>>(
        o_p0, o_p1, opb, ow16, o_b, gamma, x, out);
}